// Round 11
// baseline (233.915 us; speedup 1.0000x reference)
//
#include <hip/hip_runtime.h>
#include <hip/hip_bf16.h>

// Causal MHA forward, B=4 H=16 S=2048 D=64, fp32 I/O, bf16 MFMA compute.
// R15: phase diversity via independent co-resident workgroups.
// Falsified so far: latency exposure (R10 null), occupancy-in-one-WG (R9
// null), barrier count (R11 null), VALU issue (R14: VALUBusy -5pts, dur
// flat), banks (0.6M), HBM (<17%).  Unifying explanation: grid=256 -> ONE
// WG/CU, its 8 waves barrier-locked through the same phase sequence
// (QK-MFMA | softmax | commit+barrier) -> pipes used SEQUENTIALLY, wall =
// sum of phases (~5800cyc/tile, matches).  R9 added waves in the SAME WG =
// still lockstepped.  Fix: 512 WGs (8 q-blocks x 64 bh, unpaired) of 256
// threads (4 waves), each wave owns TWO 32-row strips.  Two WGs/CU
// (LDS 2x36.9KB, launch_bounds(256,2)) are not barrier-synced -> one WG's
// MFMA phase overlaps the other's softmax/commit phase.  Totals unchanged:
// staged tiles per bh 144 (= paired), FETCH same, K-frag LDS reads amortized
// over 2x MFMA.  Big q-blocks first (qblk = 7-bid/64) to pack the grid;
// bid%8==bh%8 XCD co-location kept.
// Kept: mfma_f32_32x32x16_bf16, in-register P via cvt_pk(pk2=v_cvt_pk_bf16_f32)
// + v_permlane32_swap_b32, in-lane denom tree + permlane/bpermute epilogue,
// double-buffered K/V LDS + register prefetch (plain C++ loads, compiler
// waitcnts -- no asm staging, R12 lesson), one barrier/tile, no-max flash
// softmax (exp2, log2e in Q scale), stride-72 2-way-free layouts.

typedef float  f32x4   __attribute__((ext_vector_type(4)));
typedef float  f32x16  __attribute__((ext_vector_type(16)));
typedef short  bf16x8  __attribute__((ext_vector_type(8)));

#define NH      16
#define DH      64
#define SEQ     2048
#define NSTATE  1024
#define ROW3    3072
#define BQ      256
#define BK      64
#define NQB     (SEQ / BQ)      // 8 q-blocks of 256
#define KST     72
#define VST     72
#define NEG_BIG (-1e9f)
#define QSC     (0.125f * 1.4426950408889634f)   // 1/sqrt(64) * log2(e)

// pack two fp32 -> two RNE bf16 in one u32 (low16=bf16(x), high16=bf16(y));
// lowers to a single v_cvt_pk_bf16_f32 (compiler-scheduled, no asm).
static __device__ __forceinline__ unsigned pk2(float x, float y) {
    float2 f2; f2.x = x; f2.y = y;
    __hip_bfloat162 b = __float22bfloat162_rn(f2);
    unsigned r;
    __builtin_memcpy(&r, &b, 4);
    return r;
}

// ---- staging (256 threads): issue global loads into regs (no wait) ------
// K: 64kv x 64d fp32 float4: p=tid+256i (i<4), kv=p>>4, d=4*(p&15).
// V: scalar row-pairs, 2-way-free transpose: i<8: d=(tid&15)+16*(i&3),
//    kv=2*((tid>>4)+16*(i>>2)); loads rows kv,kv+1 at col d.
#define ISSUE_STAGE(KV0)                                                       \
    {                                                                          \
        _Pragma("unroll")                                                      \
        for (int i = 0; i < 4; ++i) {                                          \
            int p  = tid + 256 * i;                                            \
            int kv = p >> 4;                                                   \
            int d  = (p & 15) * 4;                                             \
            kp[i] = *(const f32x4*)(kbase + (size_t)((KV0) + kv) * ROW3 + d);  \
        }                                                                      \
        _Pragma("unroll")                                                      \
        for (int i = 0; i < 8; ++i) {                                          \
            int d  = (tid & 15) + 16 * (i & 3);                                \
            int kv = 2 * ((tid >> 4) + 16 * (i >> 2));                         \
            const float* gp = vbase + (size_t)((KV0) + kv) * ROW3 + d;         \
            vp[2 * i]     = gp[0];                                             \
            vp[2 * i + 1] = gp[ROW3];                                          \
        }                                                                      \
    }

// ---- staging: convert prefetched regs -> bf16 LDS tile ------------------
#define COMMIT_STAGE(BUF)                                                      \
    {                                                                          \
        _Pragma("unroll")                                                      \
        for (int i = 0; i < 4; ++i) {                                          \
            int p  = tid + 256 * i;                                            \
            int kv = p >> 4;                                                   \
            int d  = (p & 15) * 4;                                             \
            uint2 w;                                                           \
            w.x = pk2(kp[i][0], kp[i][1]);                                     \
            w.y = pk2(kp[i][2], kp[i][3]);                                     \
            *(uint2*)&Klds[BUF][kv * KST + d] = w;                             \
        }                                                                      \
        _Pragma("unroll")                                                      \
        for (int i = 0; i < 8; ++i) {                                          \
            int d  = (tid & 15) + 16 * (i & 3);                                \
            int kv = 2 * ((tid >> 4) + 16 * (i >> 2));                         \
            *(unsigned*)&Vlds[BUF][d * VST + kv] = pk2(vp[2 * i], vp[2 * i + 1]); \
        }                                                                      \
    }

// ---- one 32-row strip's work vs the current 32-kv half ------------------
// kf[4] (shared) must already be loaded; QSTRIP = strip base row.
#define COMPUTE_STRIP(QF, O0, O1, DL, QSTRIP)                                  \
    {                                                                          \
        f32x16 s;                                                              \
        _Pragma("unroll")                                                      \
        for (int r = 0; r < 16; ++r) s[r] = 0.f;                               \
        _Pragma("unroll")                                                      \
        for (int kc = 0; kc < 4; ++kc)                                         \
            s = __builtin_amdgcn_mfma_f32_32x32x16_bf16(kf[kc], QF[kc], s, 0, 0, 0); \
        if (kvb + 31 > (QSTRIP)) {                                             \
            _Pragma("unroll")                                                  \
            for (int r = 0; r < 16; ++r) {                                     \
                int kvg = kvb + (r & 3) + 8 * (r >> 2) + 4 * hl;               \
                if (kvg > (QSTRIP) + r31) s[r] = NEG_BIG;                      \
            }                                                                  \
        }                                                                      \
        _Pragma("unroll")                                                      \
        for (int r = 0; r < 16; ++r)                                           \
            s[r] = __builtin_amdgcn_exp2f(s[r]);                               \
        {                                                                      \
            float a0 = (s[0] + s[1]) + (s[2] + s[3]);                          \
            float a1 = (s[4] + s[5]) + (s[6] + s[7]);                          \
            float a2 = (s[8] + s[9]) + (s[10] + s[11]);                        \
            float a3 = (s[12] + s[13]) + (s[14] + s[15]);                      \
            DL += (a0 + a1) + (a2 + a3);                                       \
        }                                                                      \
        _Pragma("unroll")                                                      \
        for (int cc = 0; cc < 2; ++cc) {                                       \
            unsigned wA = pk2(s[8 * cc + 0], s[8 * cc + 1]);                   \
            unsigned wB = pk2(s[8 * cc + 2], s[8 * cc + 3]);                   \
            unsigned wC = pk2(s[8 * cc + 4], s[8 * cc + 5]);                   \
            unsigned wD = pk2(s[8 * cc + 6], s[8 * cc + 7]);                   \
            __asm__ volatile("v_permlane32_swap_b32 %0, %1"                    \
                             : "+v"(wA), "+v"(wC));                            \
            __asm__ volatile("v_permlane32_swap_b32 %0, %1"                    \
                             : "+v"(wB), "+v"(wD));                            \
            union { bf16x8 v; unsigned u[4]; } pa;                             \
            pa.u[0] = wA; pa.u[1] = wB; pa.u[2] = wC; pa.u[3] = wD;            \
            const int c = 2 * H + cc;                                          \
            bf16x8 vf0 = *(const bf16x8*)&Vlds[cur][(r31)      * VST + 16 * c + 8 * hl]; \
            bf16x8 vf1 = *(const bf16x8*)&Vlds[cur][(32 + r31) * VST + 16 * c + 8 * hl]; \
            O0 = __builtin_amdgcn_mfma_f32_32x32x16_bf16(pa.v, vf0, O0, 0, 0, 0); \
            O1 = __builtin_amdgcn_mfma_f32_32x32x16_bf16(pa.v, vf1, O1, 0, 0, 0); \
        }                                                                      \
    }

#define EPILOGUE(O0, O1, DL, QSTRIP)                                           \
    {                                                                          \
        unsigned da = __builtin_bit_cast(unsigned, DL);                        \
        unsigned db = da;                                                      \
        __asm__ volatile("v_permlane32_swap_b32 %0, %1" : "+v"(da), "+v"(db)); \
        float dtot = __builtin_bit_cast(float, da) + __builtin_bit_cast(float, db); \
        float rcp  = 1.0f / dtot;                                              \
        _Pragma("unroll")                                                      \
        for (int r = 0; r < 16; ++r) {                                         \
            int srcq = (r & 3) + 8 * (r >> 2) + 4 * hl;                        \
            float lr = __builtin_bit_cast(float,                               \
                __builtin_amdgcn_ds_bpermute(srcq << 2,                        \
                    __builtin_bit_cast(int, rcp)));                            \
            const size_t row = (size_t)((QSTRIP) + srcq) * NSTATE;             \
            ob[row + r31]      = O0[r] * lr;                                   \
            ob[row + 32 + r31] = O1[r] * lr;                                   \
        }                                                                      \
    }

__global__ __launch_bounds__(256, 2)
void mha_fwd(const float* __restrict__ x, float* __restrict__ out) {
    const int tid  = threadIdx.x;
    const int wave = tid >> 6;        // 0..3 : one 64-row strip pair each
    const int lane = tid & 63;
    const int r31  = lane & 31;       // MFMA row/col lane index
    const int hl   = lane >> 5;       // lane half

    const int bid  = blockIdx.x;      // 0..511 ; bid%8 == bh%8 -> XCD co-location
    const int qblk = 7 - (bid >> 6);  // descending work: 32-tile WGs dispatch first
    const int bh   = bid & 63;
    const int b    = bh >> 4;
    const int h    = bh & 15;

    const float* xb    = x + (size_t)b * SEQ * ROW3;
    const float* kbase = xb + NSTATE + h * DH;
    const float* vbase = xb + 2 * NSTATE + h * DH;
    float*       ob    = out + (size_t)b * SEQ * NSTATE + h * DH;

    __shared__ __align__(16) short Klds[2][BK * KST];    // K[kv][d]   bf16, dbuf
    __shared__ __align__(16) short Vlds[2][DH * VST];    // V^T[d][kv] bf16, dbuf

    // prefetch registers
    f32x4 kp[4];
    float vp[16];

    const int q0  = qblk * BQ;
    const int qsA = q0 + wave * 64;        // strip A rows [qsA, qsA+32)
    const int qsB = qsA + 32;              // strip B rows [qsB, qsB+32)

    // ---- Q fragments for both strips, scaled by QSC ----
    bf16x8 qfA[4], qfB[4];
    {
        const float* qpA = xb + (size_t)(qsA + r31) * ROW3 + h * DH + hl * 8;
        const float* qpB = xb + (size_t)(qsB + r31) * ROW3 + h * DH + hl * 8;
#pragma unroll
        for (int kc = 0; kc < 4; ++kc) {
            f32x4 a = *(const f32x4*)(qpA + 16 * kc);
            f32x4 c = *(const f32x4*)(qpA + 16 * kc + 4);
            union { bf16x8 v; unsigned u[4]; } qq;
            qq.u[0] = pk2(a[0] * QSC, a[1] * QSC);
            qq.u[1] = pk2(a[2] * QSC, a[3] * QSC);
            qq.u[2] = pk2(c[0] * QSC, c[1] * QSC);
            qq.u[3] = pk2(c[2] * QSC, c[3] * QSC);
            qfA[kc] = qq.v;
            a = *(const f32x4*)(qpB + 16 * kc);
            c = *(const f32x4*)(qpB + 16 * kc + 4);
            qq.u[0] = pk2(a[0] * QSC, a[1] * QSC);
            qq.u[1] = pk2(a[2] * QSC, a[3] * QSC);
            qq.u[2] = pk2(c[0] * QSC, c[1] * QSC);
            qq.u[3] = pk2(c[2] * QSC, c[3] * QSC);
            qfB[kc] = qq.v;
        }
    }

    f32x16 oA0, oA1, oB0, oB1;
#pragma unroll
    for (int r = 0; r < 16; ++r) { oA0[r] = 0.f; oA1[r] = 0.f; oB0[r] = 0.f; oB1[r] = 0.f; }
    float dlA = 0.f, dlB = 0.f;

    const int ntiles = q0 / BK + BQ / BK;  // 4*qblk + 4

    ISSUE_STAGE(0)
    COMMIT_STAGE(0)
    __syncthreads();

#pragma unroll 1
    for (int it = 0; it < ntiles; ++it) {
        const int kv0 = it * BK;
        const int cur = it & 1;
        const bool pf = (it + 1 < ntiles);

        // issue next tile's global loads early; latency hides under compute
        if (pf) ISSUE_STAGE((it + 1) * BK)

        if (kv0 <= qsB + 31) {             // wave not fully masked
#pragma unroll
            for (int H = 0; H < 2; ++H) {  // two 32-kv halves
                const int kvb = kv0 + 32 * H;
                if (kvb <= qsB + 31) {     // strip B active (wave-uniform)
                    // K fragments (A-operand), shared by both strips
                    bf16x8 kf[4];
#pragma unroll
                    for (int kc = 0; kc < 4; ++kc)
                        kf[kc] = *(const bf16x8*)&Klds[cur][(32 * H + r31) * KST + 16 * kc + 8 * hl];

                    if (kvb <= qsA + 31) COMPUTE_STRIP(qfA, oA0, oA1, dlA, qsA)
                    COMPUTE_STRIP(qfB, oB0, oB1, dlB, qsB)
                }
            }
        }

        if (pf) COMMIT_STAGE(cur ^ 1)
        __syncthreads();
    }

    EPILOGUE(oA0, oA1, dlA, qsA)
    EPILOGUE(oB0, oB1, dlB, qsB)
}

extern "C" void kernel_launch(void* const* d_in, const int* in_sizes, int n_in,
                              void* d_out, int out_size, void* d_ws, size_t ws_size,
                              hipStream_t stream) {
    const float* x = (const float*)d_in[0];   // [B,S,3*NSTATE] fp32
    // d_in[1] (attn_mask) is not read: the mask is causal and computed inline.
    float* out = (float*)d_out;               // [B,S,NSTATE] fp32
    dim3 grid(NQB * 4 * NH);                  // 512 WGs, 1D (bid%8 == bh%8)
    dim3 block(256);
    hipLaunchKernelGGL(mha_fwd, grid, block, 0, stream, x, out);
}

// Round 12
// 231.948 us; speedup vs baseline: 1.0085x; 1.0085x over previous
//
#include <hip/hip_runtime.h>
#include <hip/hip_bf16.h>

// Causal MHA forward, B=4 H=16 S=2048 D=64, fp32 I/O, bf16 MFMA compute.
// R16: drop LDS staging entirely (guide Common-mistake #7: K/V per (b,h) is
// 512 KB bf16 = L2-resident; 8 co-located bh = 4 MB = one XCD L2).  All
// stage->barrier->compute levers were exhausted (R9/R10/R11/R14/R15 null):
// the template was the bottleneck -- 8 waves barrier-locked per tile around
// staging of cache-resident data.
// Structure:
//   kernel 1 (prep): one-time fp32->bf16 convert into d_ws.
//     K''[bh][kc][hl][kv 0..2047][j 0..7]  (fragment-major: one 16B load per
//       MFMA A-fragment, coalesced across lanes)
//     V''[bh][kv>>3][d 0..63][j=kv&7]      (transposed-tiled: one 16B load per
//       PV B-fragment, coalesced across lanes; LDS-transposed in prep)
//   kernel 2 (main): per-wave-independent flash attn.  One wave = one 32-row
//     q strip; loop over 32-kv halves; kf/vf = direct 16B global loads
//     (L1-hot); NO __shared__, NO __syncthreads -> waves desynchronize,
//     stalls decorrelate, compiler pipelines loads freely.  Grid 1024 x 256
//     (4 waves/WG, strips big-first for dynamic balance, bid%8==bh%8 XCD
//     co-location).  4 waves/SIMD via __launch_bounds__(256,4).
// Kept math (R7-R14 proven): mfma_f32_32x32x16_bf16, no-max flash softmax
// (exp2, log2e folded into Q scale), in-register P via v_cvt_pk_bf16_f32
// (pk2) + v_permlane32_swap_b32, in-lane denom tree + permlane/bpermute
// epilogue.

typedef float  f32x4   __attribute__((ext_vector_type(4)));
typedef float  f32x16  __attribute__((ext_vector_type(16)));
typedef short  bf16x8  __attribute__((ext_vector_type(8)));

#define NH      16
#define DH      64
#define SEQ     2048
#define NSTATE  1024
#define ROW3    3072
#define NEG_BIG (-1e9f)
#define QSC     (0.125f * 1.4426950408889634f)   // 1/sqrt(64) * log2(e)
#define BH_ELEMS 131072                          // 2048*64 shorts per (b,h)
#define VOFF_WS  8388608                         // K'' total shorts (64 bh)

// pack two fp32 -> two RNE bf16 in one u32 (low16=bf16(x), high16=bf16(y));
// lowers to a single v_cvt_pk_bf16_f32 (compiler-scheduled, no asm).
static __device__ __forceinline__ unsigned pk2(float x, float y) {
    float2 f2; f2.x = x; f2.y = y;
    __hip_bfloat162 b = __float22bfloat162_rn(f2);
    unsigned r;
    __builtin_memcpy(&r, &b, 4);
    return r;
}

// ---------------- kernel 1: layout/convert pre-pass ----------------------
// grid 2048 = 32 kv-tiles x 64 bh ; 512 threads.
__global__ __launch_bounds__(512)
void mha_prep(const float* __restrict__ x, short* __restrict__ ws) {
    const int tid = threadIdx.x;
    const int bid = blockIdx.x;
    const int bh  = bid & 63;
    const int kv0 = (bid >> 6) * 64;
    const int b = bh >> 4, h = bh & 15;

    const float* kb = x + (size_t)b * SEQ * ROW3 + NSTATE + h * DH;
    const float* vb = x + (size_t)b * SEQ * ROW3 + 2 * NSTATE + h * DH;
    short* wsK = ws + (size_t)bh * BH_ELEMS;
    short* wsV = ws + VOFF_WS + (size_t)bh * BH_ELEMS;

    __shared__ __align__(16) short Vt[DH * 72];   // V^T[d][kv], 2-way-free

    // K: coalesced float4 reads -> fragment-major K''
#pragma unroll
    for (int i = 0; i < 2; ++i) {
        int p  = tid + 512 * i;
        int kv = p >> 4;
        int d0 = (p & 15) * 4;
        f32x4 v = *(const f32x4*)(kb + (size_t)(kv0 + kv) * ROW3 + d0);
        uint2 w;
        w.x = pk2(v[0], v[1]);
        w.y = pk2(v[2], v[3]);
        int kc = d0 >> 4, hl = (d0 >> 3) & 1;
        *(uint2*)&wsK[((kc * 2 + hl) * 2048 + kv0 + kv) * 8 + (d0 & 7)] = w;
    }
    // V: row-pair scalar loads -> LDS transpose (R7-proven scheme)
#pragma unroll
    for (int i = 0; i < 4; ++i) {
        int d  = (tid & 15) + 16 * i;
        int kv = (tid >> 4) * 2;
        const float* gp = vb + (size_t)(kv0 + kv) * ROW3 + d;
        *(unsigned*)&Vt[d * 72 + kv] = pk2(gp[0], gp[ROW3]);
    }
    __syncthreads();
    // LDS -> V'' (coalesced 16B per thread)
    {
        int kvb = tid >> 6;        // 0..7 (8-kv block within tile)
        int d   = tid & 63;
        bf16x8 v = *(const bf16x8*)&Vt[d * 72 + kvb * 8];
        *(bf16x8*)&wsV[(((kv0 >> 3) + kvb) * 64 + d) * 8] = v;
    }
}

// ---------------- kernel 2: barrier-free per-wave flash attention --------
// grid 1024 = 16 strip-groups x 64 bh ; 256 threads = 4 waves.
__global__ __launch_bounds__(256, 4)
void mha_fwd(const float* __restrict__ x, const short* __restrict__ ws,
             float* __restrict__ out) {
    const int tid  = threadIdx.x;
    const int w    = tid >> 6;
    const int lane = tid & 63;
    const int r31  = lane & 31;
    const int hl   = lane >> 5;

    const int bid   = blockIdx.x;          // bid%8 == bh%8 -> XCD co-location
    const int bh    = bid & 63;
    const int g     = bid >> 6;            // 0..15
    const int strip = 4 * (15 - g) + w;    // 0..63, biggest strips first
    const int b = bh >> 4, h = bh & 15;

    const float* xb  = x + (size_t)b * SEQ * ROW3;
    float*       ob  = out + (size_t)b * SEQ * NSTATE + h * DH;
    const short* wsK = ws + (size_t)bh * BH_ELEMS;
    const short* wsV = ws + VOFF_WS + (size_t)bh * BH_ELEMS;

    const int qs   = strip * 32;           // strip rows [qs, qs+32)
    const int qrow = qs + r31;             // this lane's q (col of S^T)

    // ---- Q fragments (B-operand of S^T), scaled by QSC ----
    bf16x8 qf[4];
    {
        const float* qp = xb + (size_t)qrow * ROW3 + h * DH + hl * 8;
#pragma unroll
        for (int kc = 0; kc < 4; ++kc) {
            f32x4 a = *(const f32x4*)(qp + 16 * kc);
            f32x4 c = *(const f32x4*)(qp + 16 * kc + 4);
            union { bf16x8 v; unsigned u[4]; } qq;
            qq.u[0] = pk2(a[0] * QSC, a[1] * QSC);
            qq.u[1] = pk2(a[2] * QSC, a[3] * QSC);
            qq.u[2] = pk2(c[0] * QSC, c[1] * QSC);
            qq.u[3] = pk2(c[2] * QSC, c[3] * QSC);
            qf[kc] = qq.v;
        }
    }

    f32x16 o0, o1;                 // O[q 32][d 0..31], [d 32..63]
#pragma unroll
    for (int r = 0; r < 16; ++r) { o0[r] = 0.f; o1[r] = 0.f; }
    float dl = 0.f;                // per-lane softmax denominator (q = r31)

#pragma unroll 1
    for (int kvb = 0; kvb <= qs; kvb += 32) {
        // fragment loads, all hoisted to the top (no barrier -> compiler
        // pipelines these across iterations; L1-hot after first wave)
        bf16x8 kf[4];
#pragma unroll
        for (int kc = 0; kc < 4; ++kc)
            kf[kc] = *(const bf16x8*)&wsK[((kc * 2 + hl) * 2048 + kvb + r31) * 8];
        bf16x8 vfa[2], vfb[2];
#pragma unroll
        for (int cc = 0; cc < 2; ++cc) {
            const int kvblk = (kvb >> 3) + 2 * cc + hl;
            vfa[cc] = *(const bf16x8*)&wsV[(kvblk * 64 + r31) * 8];
            vfb[cc] = *(const bf16x8*)&wsV[(kvblk * 64 + 32 + r31) * 8];
        }

        // S^T half tile: 32kv x 32q
        f32x16 s;
#pragma unroll
        for (int r = 0; r < 16; ++r) s[r] = 0.f;
#pragma unroll
        for (int kc = 0; kc < 4; ++kc)
            s = __builtin_amdgcn_mfma_f32_32x32x16_bf16(kf[kc], qf[kc], s, 0, 0, 0);

        if (kvb == qs) {                    // diagonal half (wave-uniform)
#pragma unroll
            for (int r = 0; r < 16; ++r) {
                int kvg = kvb + (r & 3) + 8 * (r >> 2) + 4 * hl;
                if (kvg > qrow) s[r] = NEG_BIG;
            }
        }
#pragma unroll
        for (int r = 0; r < 16; ++r)
            s[r] = __builtin_amdgcn_exp2f(s[r]);

        // denominator: tree sum (masked elems are 0)
        {
            float a0 = (s[0] + s[1]) + (s[2] + s[3]);
            float a1 = (s[4] + s[5]) + (s[6] + s[7]);
            float a2 = (s[8] + s[9]) + (s[10] + s[11]);
            float a3 = (s[12] + s[13]) + (s[14] + s[15]);
            dl += (a0 + a1) + (a2 + a3);
        }

        // P -> bf16 A-fragments in-register (2 chunks of 16 kv)
#pragma unroll
        for (int cc = 0; cc < 2; ++cc) {
            unsigned wA = pk2(s[8 * cc + 0], s[8 * cc + 1]);
            unsigned wB = pk2(s[8 * cc + 2], s[8 * cc + 3]);
            unsigned wC = pk2(s[8 * cc + 4], s[8 * cc + 5]);
            unsigned wD = pk2(s[8 * cc + 6], s[8 * cc + 7]);
            __asm__ volatile("v_permlane32_swap_b32 %0, %1" : "+v"(wA), "+v"(wC));
            __asm__ volatile("v_permlane32_swap_b32 %0, %1" : "+v"(wB), "+v"(wD));
            union { bf16x8 v; unsigned u[4]; } pa;
            pa.u[0] = wA; pa.u[1] = wB; pa.u[2] = wC; pa.u[3] = wD;

            o0 = __builtin_amdgcn_mfma_f32_32x32x16_bf16(pa.v, vfa[cc], o0, 0, 0, 0);
            o1 = __builtin_amdgcn_mfma_f32_32x32x16_bf16(pa.v, vfb[cc], o1, 0, 0, 0);
        }
    }

    // ---- epilogue ----
    {
        unsigned da = __builtin_bit_cast(unsigned, dl);
        unsigned db = da;
        __asm__ volatile("v_permlane32_swap_b32 %0, %1" : "+v"(da), "+v"(db));
        float dtot = __builtin_bit_cast(float, da) + __builtin_bit_cast(float, db);
        float rcp  = 1.0f / dtot;              // valid in all lanes for q=r31
#pragma unroll
        for (int r = 0; r < 16; ++r) {
            int srcq = (r & 3) + 8 * (r >> 2) + 4 * hl;   // O row for reg r
            float lr = __builtin_bit_cast(float,
                __builtin_amdgcn_ds_bpermute(srcq << 2,
                    __builtin_bit_cast(int, rcp)));
            const size_t row = (size_t)(qs + srcq) * NSTATE;
            ob[row + r31]      = o0[r] * lr;
            ob[row + 32 + r31] = o1[r] * lr;
        }
    }
}

extern "C" void kernel_launch(void* const* d_in, const int* in_sizes, int n_in,
                              void* d_out, int out_size, void* d_ws, size_t ws_size,
                              hipStream_t stream) {
    const float* x = (const float*)d_in[0];   // [B,S,3*NSTATE] fp32
    // d_in[1] (attn_mask) is not read: the mask is causal and computed inline.
    float* out = (float*)d_out;               // [B,S,NSTATE] fp32
    short* ws  = (short*)d_ws;                // needs 2 x 16.78 MB = 33.6 MB

    hipLaunchKernelGGL(mha_prep, dim3(2048), dim3(512), 0, stream, x, ws);
    hipLaunchKernelGGL(mha_fwd,  dim3(1024), dim3(256), 0, stream, x, ws, out);
}